// Round 6
// baseline (289.581 us; speedup 1.0000x reference)
//
#include <hip/hip_runtime.h>
#include <hip/hip_bf16.h>

// Problem constants (fixed by setup_inputs)
#define E_TOTAL 262144
#define NG      128
#define GRAPHS  64
#define NHEADS  8
#define DKH     64
#define DMODEL  512
#define NNODES  8192

typedef __bf16 bf16x8 __attribute__((ext_vector_type(8)));
typedef float  f32x4  __attribute__((ext_vector_type(4)));
typedef unsigned short u16x8 __attribute__((ext_vector_type(8)));

__device__ inline __hip_bfloat16 f2hbf(float f) { return __float2bfloat16(f); }
__device__ inline unsigned short f2u16(float f) {
    return __builtin_bit_cast(unsigned short, __float2bfloat16(f));
}
__device__ inline __bf16 f2bf(float f) {
    return __builtin_bit_cast(__bf16, f2u16(f));
}

// ---------------------------------------------------------------------------
// Convert x (fp32) -> xb (bf16), 4 elements/thread
// ---------------------------------------------------------------------------
__global__ __launch_bounds__(256) void convert_x_kernel(
    const float* __restrict__ x, __hip_bfloat16* __restrict__ xb)
{
    int idx = (blockIdx.x * 256 + threadIdx.x) * 4;
    float4 v = *(const float4*)(x + idx);
    ushort4 o;
    o.x = f2u16(v.x); o.y = f2u16(v.y); o.z = f2u16(v.z); o.w = f2u16(v.w);
    *(ushort4*)((unsigned short*)xb + idx) = o;
}

// ---------------------------------------------------------------------------
// Prep: transpose+cast Wq|Wk|Wv (fp32, K-major) -> wqkvt (bf16, 1536x512
// N-major), Wo -> wot; pack edge-MLP weights (fp32 passthrough, transposed W1).
// ---------------------------------------------------------------------------
__global__ __launch_bounds__(256) void prep_kernel(
    const float* __restrict__ Wq, const float* __restrict__ Wk,
    const float* __restrict__ Wv, const float* __restrict__ Wo,
    const float* __restrict__ W1, const float* __restrict__ b1,
    const float* __restrict__ W2, const float* __restrict__ b2,
    __hip_bfloat16* __restrict__ wqkvt, __hip_bfloat16* __restrict__ wot,
    float* __restrict__ w1t, float* __restrict__ b1f,
    float* __restrict__ w2f, float* __restrict__ b2f)
{
    int blk = blockIdx.x, tid = threadIdx.x;
    if (blk < 256) {
        __shared__ __align__(16) __hip_bfloat16 tile[64][65];
        const float* src;
        __hip_bfloat16* dstT;
        int n0, k0, nb;
        if (blk < 192) {
            int nt = blk % 24, ktile = blk / 24;
            n0 = nt * 64; k0 = ktile * 64;
            if (n0 < 512)       { src = Wq; nb = n0; }
            else if (n0 < 1024) { src = Wk; nb = n0 - 512; }
            else                { src = Wv; nb = n0 - 1024; }
            dstT = wqkvt;
        } else {
            int t = blk - 192;
            n0 = (t % 8) * 64; k0 = (t / 8) * 64; nb = n0;
            src = Wo; dstT = wot;
        }
        #pragma unroll
        for (int i = 0; i < 16; ++i) {
            int idx = tid + i * 256;
            int kr = idx >> 6, nc = idx & 63;
            tile[kr][nc] = f2hbf(src[(size_t)(k0 + kr) * 512 + nb + nc]);
        }
        __syncthreads();
        #pragma unroll
        for (int i = 0; i < 16; ++i) {
            int idx = tid + i * 256;
            int nr = idx >> 6, kc = idx & 63;
            dstT[(size_t)(n0 + nr) * 512 + k0 + kc] = tile[kc][nr];
        }
    } else {
        // W1 is (4,512): w1t[k*4+f] = W1[f][k]
        for (int i = tid; i < 2048; i += 256) w1t[i] = W1[(size_t)(i & 3) * 512 + (i >> 2)];
        for (int i = tid; i < 512;  i += 256) b1f[i] = b1[i];
        for (int i = tid; i < 4096; i += 256) w2f[i] = W2[i];   // (512,8) row-major
        if (tid < 8) b2f[tid] = b2[tid];
    }
}

// ---------------------------------------------------------------------------
// Edge MLP: bias[h][e] = relu(ea[e] @ W1 + b1) @ W2 + b2  (fp32, fused).
// 2 edges per thread: doubles FMA per wave-uniform s_load of weights.
// ---------------------------------------------------------------------------
__global__ __launch_bounds__(256) void edge_mlp_kernel(
    const float* __restrict__ ea,
    const float* __restrict__ w1t, const float* __restrict__ b1f,
    const float* __restrict__ w2f, const float* __restrict__ b2f,
    float* __restrict__ biasE)
{
    int e0 = blockIdx.x * 512 + threadIdx.x;   // edges e0 and e0+256
    float4 xa = *(const float4*)(ea + (size_t)e0 * 4);
    float4 xb = *(const float4*)(ea + (size_t)(e0 + 256) * 4);
    float acc0[8], acc1[8];
    #pragma unroll
    for (int u = 0; u < 8; ++u) { acc0[u] = 0.f; acc1[u] = 0.f; }
    #pragma unroll 4
    for (int k = 0; k < 512; ++k) {
        float4 w1 = *(const float4*)(w1t + 4 * k);
        float b1k = b1f[k];
        float4 wa = *(const float4*)(w2f + 8 * k);
        float4 wb = *(const float4*)(w2f + 8 * k + 4);
        float h0 = b1k, h1 = b1k;
        h0 = fmaf(xa.x, w1.x, h0); h0 = fmaf(xa.y, w1.y, h0);
        h0 = fmaf(xa.z, w1.z, h0); h0 = fmaf(xa.w, w1.w, h0);
        h1 = fmaf(xb.x, w1.x, h1); h1 = fmaf(xb.y, w1.y, h1);
        h1 = fmaf(xb.z, w1.z, h1); h1 = fmaf(xb.w, w1.w, h1);
        h0 = fmaxf(h0, 0.0f);
        h1 = fmaxf(h1, 0.0f);
        acc0[0] = fmaf(h0, wa.x, acc0[0]); acc1[0] = fmaf(h1, wa.x, acc1[0]);
        acc0[1] = fmaf(h0, wa.y, acc0[1]); acc1[1] = fmaf(h1, wa.y, acc1[1]);
        acc0[2] = fmaf(h0, wa.z, acc0[2]); acc1[2] = fmaf(h1, wa.z, acc1[2]);
        acc0[3] = fmaf(h0, wa.w, acc0[3]); acc1[3] = fmaf(h1, wa.w, acc1[3]);
        acc0[4] = fmaf(h0, wb.x, acc0[4]); acc1[4] = fmaf(h1, wb.x, acc1[4]);
        acc0[5] = fmaf(h0, wb.y, acc0[5]); acc1[5] = fmaf(h1, wb.y, acc1[5]);
        acc0[6] = fmaf(h0, wb.z, acc0[6]); acc1[6] = fmaf(h1, wb.z, acc1[6]);
        acc0[7] = fmaf(h0, wb.w, acc0[7]); acc1[7] = fmaf(h1, wb.w, acc1[7]);
    }
    #pragma unroll
    for (int hh = 0; hh < 8; ++hh) {
        float bb = b2f[hh];
        biasE[(size_t)hh * E_TOTAL + e0]       = acc0[hh] + bb;
        biasE[(size_t)hh * E_TOTAL + e0 + 256] = acc1[hh] + bb;
    }
}

// ---------------------------------------------------------------------------
// GEMM: C(MxN) = A(MxK) @ BT(NxK)^T + bias. A,BT bf16; bias fp32.
// 128x128 tile, BK=32, register-mediated staging.
// mode 0: QKV epilogue -> qkv bf16 (Q,K,V row-major) + vt (V transposed).
// mode 1: out proj -> fp32 out + bo.
// ---------------------------------------------------------------------------
__global__ __launch_bounds__(256) void gemm_kernel(
    const __hip_bfloat16* __restrict__ A, const __hip_bfloat16* __restrict__ BT,
    int mode,
    const float* __restrict__ bq, const float* __restrict__ bk,
    const float* __restrict__ bv,
    __hip_bfloat16* __restrict__ qkv, __hip_bfloat16* __restrict__ vt,
    const float* __restrict__ bo, float* __restrict__ out)
{
    const int K = 512;
    __shared__ __align__(16) __hip_bfloat16 As[128 * 32];
    __shared__ __align__(16) __hip_bfloat16 Bs[128 * 32];
    int tid = threadIdx.x;
    int lane = tid & 63, quad = lane >> 4, l16 = lane & 15;
    int wave = tid >> 6, wi = wave >> 1, wj = wave & 1;
    int row0 = blockIdx.x * 128, col0 = blockIdx.y * 128;

    f32x4 acc[4][4];
    #pragma unroll
    for (int a = 0; a < 4; a++)
        #pragma unroll
        for (int b = 0; b < 4; b++)
            #pragma unroll
            for (int r = 0; r < 4; r++) acc[a][b][r] = 0.f;

    const __hip_bfloat16* Ag0 = A + (size_t)(row0 + (tid >> 2)) * K + (tid & 3) * 8;
    const __hip_bfloat16* Ag1 = Ag0 + (size_t)64 * K;
    const __hip_bfloat16* Bg0 = BT + (size_t)(col0 + (tid >> 2)) * K + (tid & 3) * 8;
    const __hip_bfloat16* Bg1 = Bg0 + (size_t)64 * K;
    int lidx = tid * 8;

    for (int kt = 0; kt < K / 32; ++kt) {
        bf16x8 a0 = *(const bf16x8*)(Ag0 + kt * 32);
        bf16x8 a1 = *(const bf16x8*)(Ag1 + kt * 32);
        bf16x8 b0 = *(const bf16x8*)(Bg0 + kt * 32);
        bf16x8 b1 = *(const bf16x8*)(Bg1 + kt * 32);
        __syncthreads();
        *(bf16x8*)&As[lidx]        = a0;
        *(bf16x8*)&As[2048 + lidx] = a1;
        *(bf16x8*)&Bs[lidx]        = b0;
        *(bf16x8*)&Bs[2048 + lidx] = b1;
        __syncthreads();
        bf16x8 af[4], bfr[4];
        #pragma unroll
        for (int t = 0; t < 4; t++)
            af[t] = *(const bf16x8*)&As[(wi * 64 + t * 16 + l16) * 32 + quad * 8];
        #pragma unroll
        for (int t = 0; t < 4; t++)
            bfr[t] = *(const bf16x8*)&Bs[(wj * 64 + t * 16 + l16) * 32 + quad * 8];
        #pragma unroll
        for (int ti = 0; ti < 4; ti++)
            #pragma unroll
            for (int tj = 0; tj < 4; tj++)
                acc[ti][tj] = __builtin_amdgcn_mfma_f32_16x16x32_bf16(af[ti], bfr[tj], acc[ti][tj], 0, 0, 0);
    }

    #pragma unroll
    for (int ti = 0; ti < 4; ti++)
        #pragma unroll
        for (int tj = 0; tj < 4; tj++) {
            int c = col0 + wj * 64 + tj * 16 + l16;
            #pragma unroll
            for (int r = 0; r < 4; r++) {
                int rw = row0 + wi * 64 + ti * 16 + quad * 4 + r;
                float v = acc[ti][tj][r];
                if (mode == 0) {
                    float bias = (c < 512) ? bq[c] : (c < 1024) ? bk[c - 512] : bv[c - 1024];
                    v += bias;
                    qkv[(size_t)rw * 1536 + c] = f2hbf(v);
                    if (c >= 1024) {
                        int g = rw >> 7, i = rw & 127, hh = (c - 1024) >> 6, d = (c - 1024) & 63;
                        vt[(((size_t)(g * 8 + hh)) * 64 + d) * 128 + i] = f2hbf(v);
                    }
                } else {
                    out[(size_t)rw * 512 + c] = v + bo[c];
                }
            }
        }
}

// ---------------------------------------------------------------------------
// Attention (MFMA): one workgroup per (graph, head).
// S in LDS, row-major, stride 132 floats -> all accesses <=2-way bank aliasing.
// ---------------------------------------------------------------------------
#define SS 132
__global__ __launch_bounds__(256) void attn_kernel(
    const __hip_bfloat16* __restrict__ qkv,
    const __hip_bfloat16* __restrict__ vt,
    const float* __restrict__ biasE,
    const int* __restrict__ eidx,
    __hip_bfloat16* __restrict__ O)
{
    __shared__ __align__(16) float S[128 * SS];   // 67584 B
    int blk = blockIdx.x, g = blk >> 3, h = blk & 7;
    int tid = threadIdx.x, wave = tid >> 6, lane = tid & 63;
    int quad = lane >> 4, l16 = lane & 15;

    const __hip_bfloat16* qbase = qkv + (size_t)(g * 128) * 1536 + h * 64;
    const __hip_bfloat16* kbase = qbase + 512;

    // ---- QK^T: wave handles i-tiles {2w,2w+1} x all 8 j-tiles
    f32x4 acc[2][8];
    #pragma unroll
    for (int t = 0; t < 2; t++)
        #pragma unroll
        for (int j = 0; j < 8; j++)
            #pragma unroll
            for (int r = 0; r < 4; r++) acc[t][j][r] = 0.f;

    #pragma unroll
    for (int k0 = 0; k0 < 64; k0 += 32) {
        bf16x8 af[2];
        #pragma unroll
        for (int t = 0; t < 2; t++) {
            int m = wave * 32 + t * 16 + l16;
            af[t] = *(const bf16x8*)(qbase + (size_t)m * 1536 + k0 + quad * 8);
        }
        #pragma unroll
        for (int tj = 0; tj < 8; tj++) {
            int n = tj * 16 + l16;
            bf16x8 bfr = *(const bf16x8*)(kbase + (size_t)n * 1536 + k0 + quad * 8);
            #pragma unroll
            for (int t = 0; t < 2; t++)
                acc[t][tj] = __builtin_amdgcn_mfma_f32_16x16x32_bf16(af[t], bfr, acc[t][tj], 0, 0, 0);
        }
    }
    #pragma unroll
    for (int t = 0; t < 2; t++)
        #pragma unroll
        for (int tj = 0; tj < 8; tj++)
            #pragma unroll
            for (int r = 0; r < 4; r++) {
                int i = wave * 32 + t * 16 + quad * 4 + r;
                int j = tj * 16 + l16;
                S[i * SS + j] = acc[t][tj][r] * 0.125f;   // 1/sqrt(64)
            }
    __syncthreads();

    // ---- edge bias scatter (duplicates accumulate, matching .at[].add)
    for (int e2 = tid; e2 < 4096; e2 += 256) {
        int idx = g * 4096 + e2;
        int ls = eidx[idx] & 127;
        int ld = eidx[E_TOTAL + idx] & 127;
        atomicAdd(&S[ls * SS + ld], biasE[(size_t)h * E_TOTAL + idx]);
    }
    __syncthreads();

    // ---- softmax over j; wave handles 32 rows
    for (int r = wave * 32; r < wave * 32 + 32; ++r) {
        float v0 = S[r * SS + lane];
        float v1 = S[r * SS + lane + 64];
        float m = fmaxf(v0, v1);
        #pragma unroll
        for (int off = 32; off > 0; off >>= 1) m = fmaxf(m, __shfl_xor(m, off));
        float e0 = __expf(v0 - m), e1 = __expf(v1 - m);
        float s = e0 + e1;
        #pragma unroll
        for (int off = 32; off > 0; off >>= 1) s += __shfl_xor(s, off);
        float inv = 1.0f / s;
        S[r * SS + lane] = e0 * inv;
        S[r * SS + lane + 64] = e1 * inv;
    }
    __syncthreads();

    // ---- PV: O(128x64) = P @ V; A-frags are b128 LDS reads, B from vt
    f32x4 oacc[2][4];
    #pragma unroll
    for (int t = 0; t < 2; t++)
        #pragma unroll
        for (int j = 0; j < 4; j++)
            #pragma unroll
            for (int r = 0; r < 4; r++) oacc[t][j][r] = 0.f;

    const __hip_bfloat16* vbase = vt + (size_t)(g * 8 + h) * 64 * 128;
    #pragma unroll
    for (int k0 = 0; k0 < 128; k0 += 32) {
        bf16x8 af[2];
        #pragma unroll
        for (int t = 0; t < 2; t++) {
            int m = wave * 32 + t * 16 + l16;
            const float* p = &S[m * SS + k0 + quad * 8];
            f32x4 xa = *(const f32x4*)p;
            f32x4 xb = *(const f32x4*)(p + 4);
            bf16x8 a;
            a[0] = f2bf(xa[0]); a[1] = f2bf(xa[1]); a[2] = f2bf(xa[2]); a[3] = f2bf(xa[3]);
            a[4] = f2bf(xb[0]); a[5] = f2bf(xb[1]); a[6] = f2bf(xb[2]); a[7] = f2bf(xb[3]);
            af[t] = a;
        }
        #pragma unroll
        for (int tj = 0; tj < 4; tj++) {
            int d = tj * 16 + l16;
            bf16x8 bfr = *(const bf16x8*)(vbase + (size_t)d * 128 + k0 + quad * 8);
            #pragma unroll
            for (int t = 0; t < 2; t++)
                oacc[t][tj] = __builtin_amdgcn_mfma_f32_16x16x32_bf16(af[t], bfr, oacc[t][tj], 0, 0, 0);
        }
    }
    #pragma unroll
    for (int t = 0; t < 2; t++)
        #pragma unroll
        for (int tj = 0; tj < 4; tj++)
            #pragma unroll
            for (int r = 0; r < 4; r++) {
                int i = wave * 32 + t * 16 + quad * 4 + r;
                int d = tj * 16 + l16;
                O[(size_t)(g * 128 + i) * 512 + h * 64 + d] = f2hbf(oacc[t][tj][r]);
            }
}

// ---------------------------------------------------------------------------
// Workspace layout (bytes), total ~61 MB
// ---------------------------------------------------------------------------
#define WS_WQKVT 0x0          // 1536*512 bf16 = 1.5 MB
#define WS_WOT   0x180000     // 512*512 bf16 = 0.5 MB
#define WS_W1T   0x200000
#define WS_B1F   0x202000
#define WS_W2F   0x202800
#define WS_B2F   0x206800
#define WS_XB    0x210000     // 8192*512 bf16 = 8 MB
#define WS_QKV   0xA10000     // 8192*1536 bf16 = 24 MB
#define WS_VT    0x2210000    // 8 MB
#define WS_BIASE 0x2A10000    // 8*262144 fp32 = 8 MB
#define WS_O     0x3210000    // 8192*512 bf16 = 8 MB

extern "C" void kernel_launch(void* const* d_in, const int* in_sizes, int n_in,
                              void* d_out, int out_size, void* d_ws, size_t ws_size,
                              hipStream_t stream) {
    const float* x    = (const float*)d_in[0];
    const int*   eidx = (const int*)d_in[1];
    const float* ea   = (const float*)d_in[2];
    // d_in[3] = batch, d_in[4] = n_g (unused; block structure is fixed)
    const float* Wq = (const float*)d_in[5];
    const float* bq = (const float*)d_in[6];
    const float* Wk = (const float*)d_in[7];
    const float* bk = (const float*)d_in[8];
    const float* Wv = (const float*)d_in[9];
    const float* bv = (const float*)d_in[10];
    const float* Wo = (const float*)d_in[11];
    const float* bo = (const float*)d_in[12];
    const float* W1 = (const float*)d_in[13];
    const float* b1 = (const float*)d_in[14];
    const float* W2 = (const float*)d_in[15];
    const float* b2 = (const float*)d_in[16];

    char* ws = (char*)d_ws;
    __hip_bfloat16* wqkvt = (__hip_bfloat16*)(ws + WS_WQKVT);
    __hip_bfloat16* wot   = (__hip_bfloat16*)(ws + WS_WOT);
    float* w1t   = (float*)(ws + WS_W1T);
    float* b1f   = (float*)(ws + WS_B1F);
    float* w2f   = (float*)(ws + WS_W2F);
    float* b2f   = (float*)(ws + WS_B2F);
    __hip_bfloat16* xb  = (__hip_bfloat16*)(ws + WS_XB);
    __hip_bfloat16* qkv = (__hip_bfloat16*)(ws + WS_QKV);
    __hip_bfloat16* vt  = (__hip_bfloat16*)(ws + WS_VT);
    float* biasE = (float*)(ws + WS_BIASE);
    __hip_bfloat16* O   = (__hip_bfloat16*)(ws + WS_O);

    convert_x_kernel<<<NNODES * DMODEL / 1024, 256, 0, stream>>>(x, xb);
    prep_kernel<<<257, 256, 0, stream>>>(Wq, Wk, Wv, Wo, W1, b1, W2, b2,
                                         wqkvt, wot, w1t, b1f, w2f, b2f);
    edge_mlp_kernel<<<E_TOTAL / 512, 256, 0, stream>>>(ea, w1t, b1f, w2f, b2f, biasE);
    gemm_kernel<<<dim3(NNODES / 128, 1536 / 128), 256, 0, stream>>>(
        xb, wqkvt, 0, bq, bk, bv, qkv, vt, nullptr, nullptr);
    attn_kernel<<<GRAPHS * NHEADS, 256, 0, stream>>>(qkv, vt, biasE, eidx, O);
    gemm_kernel<<<dim3(NNODES / 128, 512 / 128), 256, 0, stream>>>(
        O, wot, 1, nullptr, nullptr, nullptr, nullptr, nullptr, bo, (float*)d_out);
}

// Round 7
// 268.601 us; speedup vs baseline: 1.0781x; 1.0781x over previous
//
#include <hip/hip_runtime.h>
#include <hip/hip_bf16.h>

// Problem constants (fixed by setup_inputs)
#define E_TOTAL 262144
#define NG      128
#define GRAPHS  64
#define NHEADS  8
#define DKH     64
#define DMODEL  512
#define NNODES  8192

typedef __bf16 bf16x8 __attribute__((ext_vector_type(8)));
typedef float  f32x4  __attribute__((ext_vector_type(4)));
typedef unsigned short u16x8 __attribute__((ext_vector_type(8)));

__device__ inline __hip_bfloat16 f2hbf(float f) { return __float2bfloat16(f); }
__device__ inline unsigned short f2u16(float f) {
    return __builtin_bit_cast(unsigned short, __float2bfloat16(f));
}
__device__ inline __bf16 f2bf(float f) {
    return __builtin_bit_cast(__bf16, f2u16(f));
}

// ---------------------------------------------------------------------------
// Convert x (fp32) -> xb (bf16), 4 elements/thread
// ---------------------------------------------------------------------------
__global__ __launch_bounds__(256) void convert_x_kernel(
    const float* __restrict__ x, __hip_bfloat16* __restrict__ xb)
{
    int idx = (blockIdx.x * 256 + threadIdx.x) * 4;
    float4 v = *(const float4*)(x + idx);
    ushort4 o;
    o.x = f2u16(v.x); o.y = f2u16(v.y); o.z = f2u16(v.z); o.w = f2u16(v.w);
    *(ushort4*)((unsigned short*)xb + idx) = o;
}

// ---------------------------------------------------------------------------
// Prep: transpose+cast Wq|Wk|Wv (fp32, K-major) -> wqkvt (bf16, 1536x512
// N-major), Wo -> wot; build edge-MLP MFMA frag tables:
//   w1fragt[n][j] = j<4 ? bf16(W1[j][n]) : 0         (512 x 8 bf16, 8 KB)
//   w2bt[n][k]    = n<8 ? bf16(W2[k][n]) : 0         (16 x 512 bf16, 16 KB)
// ---------------------------------------------------------------------------
__global__ __launch_bounds__(256) void prep_kernel(
    const float* __restrict__ Wq, const float* __restrict__ Wk,
    const float* __restrict__ Wv, const float* __restrict__ Wo,
    const float* __restrict__ W1, const float* __restrict__ b1,
    const float* __restrict__ W2, const float* __restrict__ b2,
    __hip_bfloat16* __restrict__ wqkvt, __hip_bfloat16* __restrict__ wot,
    __hip_bfloat16* __restrict__ w1fragt, float* __restrict__ b1f,
    __hip_bfloat16* __restrict__ w2bt, float* __restrict__ b2f)
{
    int blk = blockIdx.x, tid = threadIdx.x;
    if (blk < 256) {
        __shared__ __align__(16) __hip_bfloat16 tile[64][65];
        const float* src;
        __hip_bfloat16* dstT;
        int n0, k0, nb;
        if (blk < 192) {
            int nt = blk % 24, ktile = blk / 24;
            n0 = nt * 64; k0 = ktile * 64;
            if (n0 < 512)       { src = Wq; nb = n0; }
            else if (n0 < 1024) { src = Wk; nb = n0 - 512; }
            else                { src = Wv; nb = n0 - 1024; }
            dstT = wqkvt;
        } else {
            int t = blk - 192;
            n0 = (t % 8) * 64; k0 = (t / 8) * 64; nb = n0;
            src = Wo; dstT = wot;
        }
        #pragma unroll
        for (int i = 0; i < 16; ++i) {
            int idx = tid + i * 256;
            int kr = idx >> 6, nc = idx & 63;
            tile[kr][nc] = f2hbf(src[(size_t)(k0 + kr) * 512 + nb + nc]);
        }
        __syncthreads();
        #pragma unroll
        for (int i = 0; i < 16; ++i) {
            int idx = tid + i * 256;
            int nr = idx >> 6, kc = idx & 63;
            dstT[(size_t)(n0 + nr) * 512 + k0 + kc] = tile[kc][nr];
        }
    } else {
        __hip_bfloat16 z = f2hbf(0.f);
        // w1fragt: [512][8]
        for (int n = tid; n < 512; n += 256) {
            #pragma unroll
            for (int j = 0; j < 4; ++j) w1fragt[n * 8 + j] = f2hbf(W1[(size_t)j * 512 + n]);
            #pragma unroll
            for (int j = 4; j < 8; ++j) w1fragt[n * 8 + j] = z;
        }
        for (int i = tid; i < 512; i += 256) b1f[i] = b1[i];
        // w2bt: [16][512], W2 is (512,8) row-major
        for (int i = tid; i < 16 * 512; i += 256) {
            int n = i >> 9, k = i & 511;
            w2bt[i] = (n < 8) ? f2hbf(W2[(size_t)k * 8 + n]) : z;
        }
        if (tid < 8) b2f[tid] = b2[tid];
    }
}

// ---------------------------------------------------------------------------
// Edge MLP via MFMA: biasE[e][h] = relu(ea[e] @ W1 + b1) @ W2 + b2.
// One wave = 16 edges. Layer 1: zero-padded K=4 MFMA per 16-hidden tile;
// h round-trips through wave-private LDS; layer 2: 16 MFMAs over K=512.
// No barriers (all LDS traffic is wave-private, in-order DS pipe).
// ---------------------------------------------------------------------------
__global__ __launch_bounds__(256) void edge_mlp_kernel(
    const float* __restrict__ ea,
    const __hip_bfloat16* __restrict__ w1fragt, const float* __restrict__ b1f,
    const __hip_bfloat16* __restrict__ w2bt, const float* __restrict__ b2f,
    float* __restrict__ biasE)
{
    __shared__ __align__(16) __hip_bfloat16 hl[4][16][136];   // 17.4 KB
    int tid = threadIdx.x, wave = tid >> 6, lane = tid & 63;
    int quad = lane >> 4, l16 = lane & 15;
    int eb = blockIdx.x * 64 + wave * 16;      // this wave's 16 edges

    // Layer-1 A-frag (constant across tiles): A[m=l16(edge)][k=quad*8+j]
    // = ea[edge][k] for k<4 else 0; quads 1-3 entirely zero (B is zero there).
    bf16x8 a1 = {};
    if (quad == 0) {
        float4 e4 = *(const float4*)(ea + (size_t)(eb + l16) * 4);
        a1[0] = f2bf(e4.x); a1[1] = f2bf(e4.y); a1[2] = f2bf(e4.z); a1[3] = f2bf(e4.w);
    }

    f32x4 c2 = {0.f, 0.f, 0.f, 0.f};   // layer-2 acc: col=head=l16, row=edge=quad*4+r

    for (int ch = 0; ch < 4; ++ch) {
        // ---- layer 1: 8 tiles of 16 hidden each -> h chunk [16][128] in LDS
        #pragma unroll
        for (int t = 0; t < 8; ++t) {
            int n = ch * 128 + t * 16 + l16;
            bf16x8 bf1 = {};
            if (quad == 0)
                bf1 = *(const bf16x8*)(w1fragt + (size_t)n * 8);
            f32x4 c = {0.f, 0.f, 0.f, 0.f};
            c = __builtin_amdgcn_mfma_f32_16x16x32_bf16(a1, bf1, c, 0, 0, 0);
            float bb = b1f[n];
            #pragma unroll
            for (int r = 0; r < 4; ++r) {
                float hv = fmaxf(c[r] + bb, 0.f);
                hl[wave][quad * 4 + r][t * 16 + l16] = f2hbf(hv);
            }
        }
        // ---- layer 2: 4 K-steps of 32 over this 128-chunk
        #pragma unroll
        for (int ks = 0; ks < 4; ++ks) {
            bf16x8 af = *(const bf16x8*)&hl[wave][l16][ks * 32 + quad * 8];
            bf16x8 bf2 = *(const bf16x8*)(w2bt + (size_t)l16 * 512 + ch * 128 + ks * 32 + quad * 8);
            c2 = __builtin_amdgcn_mfma_f32_16x16x32_bf16(af, bf2, c2, 0, 0, 0);
        }
    }
    if (l16 < 8) {
        float b2v = b2f[l16];
        #pragma unroll
        for (int r = 0; r < 4; ++r) {
            int e = eb + quad * 4 + r;
            biasE[(size_t)e * 8 + l16] = c2[r] + b2v;
        }
    }
}

// ---------------------------------------------------------------------------
// GEMM: C(MxN) = A(MxK) @ BT(NxK)^T + bias. A,BT bf16; bias fp32.
// 128x128 tile, BK=32, register-mediated staging.
// mode 0: QKV epilogue -> qkv bf16 (Q,K,V row-major) + vt (V transposed).
// mode 1: out proj -> fp32 out + bo.
// ---------------------------------------------------------------------------
__global__ __launch_bounds__(256) void gemm_kernel(
    const __hip_bfloat16* __restrict__ A, const __hip_bfloat16* __restrict__ BT,
    int mode,
    const float* __restrict__ bq, const float* __restrict__ bk,
    const float* __restrict__ bv,
    __hip_bfloat16* __restrict__ qkv, __hip_bfloat16* __restrict__ vt,
    const float* __restrict__ bo, float* __restrict__ out)
{
    const int K = 512;
    __shared__ __align__(16) __hip_bfloat16 As[128 * 32];
    __shared__ __align__(16) __hip_bfloat16 Bs[128 * 32];
    int tid = threadIdx.x;
    int lane = tid & 63, quad = lane >> 4, l16 = lane & 15;
    int wave = tid >> 6, wi = wave >> 1, wj = wave & 1;
    int row0 = blockIdx.x * 128, col0 = blockIdx.y * 128;

    f32x4 acc[4][4];
    #pragma unroll
    for (int a = 0; a < 4; a++)
        #pragma unroll
        for (int b = 0; b < 4; b++)
            #pragma unroll
            for (int r = 0; r < 4; r++) acc[a][b][r] = 0.f;

    const __hip_bfloat16* Ag0 = A + (size_t)(row0 + (tid >> 2)) * K + (tid & 3) * 8;
    const __hip_bfloat16* Ag1 = Ag0 + (size_t)64 * K;
    const __hip_bfloat16* Bg0 = BT + (size_t)(col0 + (tid >> 2)) * K + (tid & 3) * 8;
    const __hip_bfloat16* Bg1 = Bg0 + (size_t)64 * K;
    int lidx = tid * 8;

    for (int kt = 0; kt < K / 32; ++kt) {
        bf16x8 a0 = *(const bf16x8*)(Ag0 + kt * 32);
        bf16x8 a1 = *(const bf16x8*)(Ag1 + kt * 32);
        bf16x8 b0 = *(const bf16x8*)(Bg0 + kt * 32);
        bf16x8 b1 = *(const bf16x8*)(Bg1 + kt * 32);
        __syncthreads();
        *(bf16x8*)&As[lidx]        = a0;
        *(bf16x8*)&As[2048 + lidx] = a1;
        *(bf16x8*)&Bs[lidx]        = b0;
        *(bf16x8*)&Bs[2048 + lidx] = b1;
        __syncthreads();
        bf16x8 af[4], bfr[4];
        #pragma unroll
        for (int t = 0; t < 4; t++)
            af[t] = *(const bf16x8*)&As[(wi * 64 + t * 16 + l16) * 32 + quad * 8];
        #pragma unroll
        for (int t = 0; t < 4; t++)
            bfr[t] = *(const bf16x8*)&Bs[(wj * 64 + t * 16 + l16) * 32 + quad * 8];
        #pragma unroll
        for (int ti = 0; ti < 4; ti++)
            #pragma unroll
            for (int tj = 0; tj < 4; tj++)
                acc[ti][tj] = __builtin_amdgcn_mfma_f32_16x16x32_bf16(af[ti], bfr[tj], acc[ti][tj], 0, 0, 0);
    }

    #pragma unroll
    for (int ti = 0; ti < 4; ti++)
        #pragma unroll
        for (int tj = 0; tj < 4; tj++) {
            int c = col0 + wj * 64 + tj * 16 + l16;
            #pragma unroll
            for (int r = 0; r < 4; r++) {
                int rw = row0 + wi * 64 + ti * 16 + quad * 4 + r;
                float v = acc[ti][tj][r];
                if (mode == 0) {
                    float bias = (c < 512) ? bq[c] : (c < 1024) ? bk[c - 512] : bv[c - 1024];
                    v += bias;
                    qkv[(size_t)rw * 1536 + c] = f2hbf(v);
                    if (c >= 1024) {
                        int g = rw >> 7, i = rw & 127, hh = (c - 1024) >> 6, d = (c - 1024) & 63;
                        vt[(((size_t)(g * 8 + hh)) * 64 + d) * 128 + i] = f2hbf(v);
                    }
                } else {
                    out[(size_t)rw * 512 + c] = v + bo[c];
                }
            }
        }
}

// ---------------------------------------------------------------------------
// Attention (MFMA): one workgroup per (graph, head).
// S in LDS, row-major, stride 132 floats -> all accesses <=2-way bank aliasing.
// ---------------------------------------------------------------------------
#define SS 132
__global__ __launch_bounds__(256) void attn_kernel(
    const __hip_bfloat16* __restrict__ qkv,
    const __hip_bfloat16* __restrict__ vt,
    const float* __restrict__ biasE,
    const int* __restrict__ eidx,
    __hip_bfloat16* __restrict__ O)
{
    __shared__ __align__(16) float S[128 * SS];   // 67584 B
    int blk = blockIdx.x, g = blk >> 3, h = blk & 7;
    int tid = threadIdx.x, wave = tid >> 6, lane = tid & 63;
    int quad = lane >> 4, l16 = lane & 15;

    const __hip_bfloat16* qbase = qkv + (size_t)(g * 128) * 1536 + h * 64;
    const __hip_bfloat16* kbase = qbase + 512;

    // ---- QK^T: wave handles i-tiles {2w,2w+1} x all 8 j-tiles
    f32x4 acc[2][8];
    #pragma unroll
    for (int t = 0; t < 2; t++)
        #pragma unroll
        for (int j = 0; j < 8; j++)
            #pragma unroll
            for (int r = 0; r < 4; r++) acc[t][j][r] = 0.f;

    #pragma unroll
    for (int k0 = 0; k0 < 64; k0 += 32) {
        bf16x8 af[2];
        #pragma unroll
        for (int t = 0; t < 2; t++) {
            int m = wave * 32 + t * 16 + l16;
            af[t] = *(const bf16x8*)(qbase + (size_t)m * 1536 + k0 + quad * 8);
        }
        #pragma unroll
        for (int tj = 0; tj < 8; tj++) {
            int n = tj * 16 + l16;
            bf16x8 bfr = *(const bf16x8*)(kbase + (size_t)n * 1536 + k0 + quad * 8);
            #pragma unroll
            for (int t = 0; t < 2; t++)
                acc[t][tj] = __builtin_amdgcn_mfma_f32_16x16x32_bf16(af[t], bfr, acc[t][tj], 0, 0, 0);
        }
    }
    #pragma unroll
    for (int t = 0; t < 2; t++)
        #pragma unroll
        for (int tj = 0; tj < 8; tj++)
            #pragma unroll
            for (int r = 0; r < 4; r++) {
                int i = wave * 32 + t * 16 + quad * 4 + r;
                int j = tj * 16 + l16;
                S[i * SS + j] = acc[t][tj][r] * 0.125f;   // 1/sqrt(64)
            }
    __syncthreads();

    // ---- edge bias scatter (duplicates accumulate, matching .at[].add)
    for (int e2 = tid; e2 < 4096; e2 += 256) {
        int idx = g * 4096 + e2;
        int ls = eidx[idx] & 127;
        int ld = eidx[E_TOTAL + idx] & 127;
        atomicAdd(&S[ls * SS + ld], biasE[(size_t)idx * 8 + h]);
    }
    __syncthreads();

    // ---- softmax over j; wave handles 32 rows
    for (int r = wave * 32; r < wave * 32 + 32; ++r) {
        float v0 = S[r * SS + lane];
        float v1 = S[r * SS + lane + 64];
        float m = fmaxf(v0, v1);
        #pragma unroll
        for (int off = 32; off > 0; off >>= 1) m = fmaxf(m, __shfl_xor(m, off));
        float e0 = __expf(v0 - m), e1 = __expf(v1 - m);
        float s = e0 + e1;
        #pragma unroll
        for (int off = 32; off > 0; off >>= 1) s += __shfl_xor(s, off);
        float inv = 1.0f / s;
        S[r * SS + lane] = e0 * inv;
        S[r * SS + lane + 64] = e1 * inv;
    }
    __syncthreads();

    // ---- PV: O(128x64) = P @ V; A-frags are b128 LDS reads, B from vt
    f32x4 oacc[2][4];
    #pragma unroll
    for (int t = 0; t < 2; t++)
        #pragma unroll
        for (int j = 0; j < 4; j++)
            #pragma unroll
            for (int r = 0; r < 4; r++) oacc[t][j][r] = 0.f;

    const __hip_bfloat16* vbase = vt + (size_t)(g * 8 + h) * 64 * 128;
    #pragma unroll
    for (int k0 = 0; k0 < 128; k0 += 32) {
        bf16x8 af[2];
        #pragma unroll
        for (int t = 0; t < 2; t++) {
            int m = wave * 32 + t * 16 + l16;
            const float* p = &S[m * SS + k0 + quad * 8];
            f32x4 xa = *(const f32x4*)p;
            f32x4 xb = *(const f32x4*)(p + 4);
            bf16x8 a;
            a[0] = f2bf(xa[0]); a[1] = f2bf(xa[1]); a[2] = f2bf(xa[2]); a[3] = f2bf(xa[3]);
            a[4] = f2bf(xb[0]); a[5] = f2bf(xb[1]); a[6] = f2bf(xb[2]); a[7] = f2bf(xb[3]);
            af[t] = a;
        }
        #pragma unroll
        for (int tj = 0; tj < 4; tj++) {
            int d = tj * 16 + l16;
            bf16x8 bfr = *(const bf16x8*)(vbase + (size_t)d * 128 + k0 + quad * 8);
            #pragma unroll
            for (int t = 0; t < 2; t++)
                oacc[t][tj] = __builtin_amdgcn_mfma_f32_16x16x32_bf16(af[t], bfr, oacc[t][tj], 0, 0, 0);
        }
    }
    #pragma unroll
    for (int t = 0; t < 2; t++)
        #pragma unroll
        for (int tj = 0; tj < 4; tj++)
            #pragma unroll
            for (int r = 0; r < 4; r++) {
                int i = wave * 32 + t * 16 + quad * 4 + r;
                int d = tj * 16 + l16;
                O[(size_t)(g * 128 + i) * 512 + h * 64 + d] = f2hbf(oacc[t][tj][r]);
            }
}

// ---------------------------------------------------------------------------
// Workspace layout (bytes), total ~61 MB
// ---------------------------------------------------------------------------
#define WS_WQKVT 0x0          // 1536*512 bf16 = 1.5 MB
#define WS_WOT   0x180000     // 512*512 bf16 = 0.5 MB
#define WS_W1FR  0x200000     // 512*8 bf16 = 8 KB
#define WS_B1F   0x202000     // 2 KB
#define WS_W2BT  0x202800     // 16*512 bf16 = 16 KB
#define WS_B2F   0x206800
#define WS_XB    0x210000     // 8192*512 bf16 = 8 MB
#define WS_QKV   0xA10000     // 8192*1536 bf16 = 24 MB
#define WS_VT    0x2210000    // 8 MB
#define WS_BIASE 0x2A10000    // 262144*8 fp32 = 8 MB ([e][h] layout)
#define WS_O     0x3210000    // 8192*512 bf16 = 8 MB

extern "C" void kernel_launch(void* const* d_in, const int* in_sizes, int n_in,
                              void* d_out, int out_size, void* d_ws, size_t ws_size,
                              hipStream_t stream) {
    const float* x    = (const float*)d_in[0];
    const int*   eidx = (const int*)d_in[1];
    const float* ea   = (const float*)d_in[2];
    // d_in[3] = batch, d_in[4] = n_g (unused; block structure is fixed)
    const float* Wq = (const float*)d_in[5];
    const float* bq = (const float*)d_in[6];
    const float* Wk = (const float*)d_in[7];
    const float* bk = (const float*)d_in[8];
    const float* Wv = (const float*)d_in[9];
    const float* bv = (const float*)d_in[10];
    const float* Wo = (const float*)d_in[11];
    const float* bo = (const float*)d_in[12];
    const float* W1 = (const float*)d_in[13];
    const float* b1 = (const float*)d_in[14];
    const float* W2 = (const float*)d_in[15];
    const float* b2 = (const float*)d_in[16];

    char* ws = (char*)d_ws;
    __hip_bfloat16* wqkvt   = (__hip_bfloat16*)(ws + WS_WQKVT);
    __hip_bfloat16* wot     = (__hip_bfloat16*)(ws + WS_WOT);
    __hip_bfloat16* w1fragt = (__hip_bfloat16*)(ws + WS_W1FR);
    float* b1f   = (float*)(ws + WS_B1F);
    __hip_bfloat16* w2bt    = (__hip_bfloat16*)(ws + WS_W2BT);
    float* b2f   = (float*)(ws + WS_B2F);
    __hip_bfloat16* xb  = (__hip_bfloat16*)(ws + WS_XB);
    __hip_bfloat16* qkv = (__hip_bfloat16*)(ws + WS_QKV);
    __hip_bfloat16* vt  = (__hip_bfloat16*)(ws + WS_VT);
    float* biasE = (float*)(ws + WS_BIASE);
    __hip_bfloat16* O   = (__hip_bfloat16*)(ws + WS_O);

    convert_x_kernel<<<NNODES * DMODEL / 1024, 256, 0, stream>>>(x, xb);
    prep_kernel<<<257, 256, 0, stream>>>(Wq, Wk, Wv, Wo, W1, b1, W2, b2,
                                         wqkvt, wot, w1fragt, b1f, w2bt, b2f);
    edge_mlp_kernel<<<E_TOTAL / 64, 256, 0, stream>>>(ea, w1fragt, b1f, w2bt, b2f, biasE);
    gemm_kernel<<<dim3(NNODES / 128, 1536 / 128), 256, 0, stream>>>(
        xb, wqkvt, 0, bq, bk, bv, qkv, vt, nullptr, nullptr);
    attn_kernel<<<GRAPHS * NHEADS, 256, 0, stream>>>(qkv, vt, biasE, eidx, O);
    gemm_kernel<<<dim3(NNODES / 128, 512 / 128), 256, 0, stream>>>(
        O, wot, 1, nullptr, nullptr, nullptr, nullptr, nullptr, bo, (float*)d_out);
}